// Round 6
// baseline (357.058 us; speedup 1.0000x reference)
//
#include <hip/hip_runtime.h>
#include <hip/hip_bf16.h>

typedef unsigned short u16;
typedef unsigned int u32;
typedef __bf16 bf16x8_t __attribute__((ext_vector_type(8)));
typedef float fx4 __attribute__((ext_vector_type(4)));
typedef float fx16 __attribute__((ext_vector_type(16)));
typedef u16 u16x8_t __attribute__((ext_vector_type(8)));
typedef u32 u32x2_t __attribute__((ext_vector_type(2)));
typedef u32 u32x4_t __attribute__((ext_vector_type(4)));

// (1/sqrt(32)) * log2(e): fold softmax scale AND exp->exp2 conversion into Q
#define QSCALE 0.25500276676267216f
#define LOG2E 1.4426950408889634f

__device__ __forceinline__ u16 f2bu(float f) {
  __bf16 h = (__bf16)f;
  return __builtin_bit_cast(u16, h);
}
// swap a.lanes[32:63] <-> b.lanes[0:31]
__device__ __forceinline__ void plswap(u32& a, u32& b) {
  u32x2_t r = __builtin_amdgcn_permlane32_swap(a, b, false, false);
  a = r[0]; b = r[1];
}

#define GLD16(gp, lp) __builtin_amdgcn_global_load_lds( \
    (const __attribute__((address_space(1))) void*)(gp), \
    (__attribute__((address_space(3))) void*)(lp), 16, 0, 0)

// ---------------- prep: weights -> bf16 (fold QSCALE into q-rows) --------------
__global__ void prep_w(const float* __restrict__ wqkv, const float* __restrict__ wout,
                       u16* __restrict__ bqkv, u16* __restrict__ bwout) {
  int t = blockIdx.x * 256 + threadIdx.x;      // 262144 threads
  if (t < 196608) {
    float v = wqkv[t];
    if (t < 65536) v *= QSCALE;                // rows 0..255 are Q rows
    bqkv[t] = f2bu(v);
  } else {
    int i = t - 196608;
    bwout[i] = f2bu(wout[i]);
  }
}

// ---- prep: bias f32 in 32x32 MFMA C-fragment layout [h][s10][t10][lane64][16] --
// S^T fragment: col = lane&31 = query, row = (r&3)+8*(r>>2)+4*(lane>>5) = key.
// Bias pre-multiplied by log2(e) (exp2-domain softmax).
__global__ void prep_bias(const float* __restrict__ table, float* __restrict__ bias_pre) {
  int t = blockIdx.x * 256 + threadIdx.x;      // 8*10*10*64 = 51200 threads
  int lane = t & 63;
  int rest = t >> 6;
  int tile = rest % 10; rest /= 10;
  int s = rest % 10; int h = rest / 10;
  int q = s * 32 + (lane & 31); if (q > 293) q = 293;   // padded q rows: clamp
  int l1 = q / 49, r1 = q % 49, a1 = r1 / 7, b1 = r1 % 7;
  fx4 o[4];
#pragma unroll
  for (int r = 0; r < 16; ++r) {
    int key = tile * 32 + (r & 3) + 8 * (r >> 2) + 4 * (lane >> 5);
    float v;
    if (key >= 294) {
      v = -1e30f;                              // mask padded key rows (exp2 -> 0)
    } else {
      int l2 = key / 49, r2 = key % 49, a2 = r2 / 7, b2 = r2 % 7;
      int idx = (l1 - l2 + 5) * 169 + (a1 - a2 + 6) * 13 + (b1 - b2 + 6);
      v = table[idx * 8 + h] * LOG2E;
    }
    o[r >> 2][r & 3] = v;
  }
  float* dst = bias_pre + (size_t)t * 16;
#pragma unroll
  for (int q4 = 0; q4 < 4; ++q4) *(fx4*)(dst + q4 * 4) = o[q4];
}

// ------- QKV GEMM, fused x-permute A-staging; epilogue -> head-major layout ----
// C layout: [win256][{q,k,v}][h8][tok294][d32]
__global__ __launch_bounds__(256, 2) void gemm_qkv(const float* __restrict__ X,
                                                   const u16* __restrict__ Bw,
                                                   u16* __restrict__ C) {
  __shared__ u16 sA[128 * 32];
  __shared__ u16 sB[128 * 32];
  const int tid = threadIdx.x, lane = tid & 63, wave = tid >> 6;
  const int wr = wave >> 1, wc = wave & 1;
  const int tm = blockIdx.x, tn = blockIdx.y;
  size_t xb[2];
#pragma unroll
  for (int rnd = 0; rnd < 2; ++rnd) {
    int row = rnd * 64 + (tid >> 2);
    int m = tm * 128 + row;
    int b = m / 294, n = m % 294;
    int hx = b >> 4, wy = b & 15;
    int l = n / 49, rem = n % 49, w1 = rem / 7, w2 = rem % 7;
    xb[rnd] = (((((size_t)l * 16 + hx) * 16 + wy) * 7 + w1) * 7 + w2) * 256 + (tid & 3) * 8;
  }
  fx4 acc[4][4] = {};
#pragma unroll 1
  for (int kt = 0; kt < 8; ++kt) {
    __syncthreads();
#pragma unroll
    for (int rnd = 0; rnd < 2; ++rnd) {
      int o = rnd * 4096 + tid * 16;
      const float4* src = (const float4*)(X + xb[rnd] + kt * 32);
      float4 v0 = src[0], v1 = src[1];
      u16x8_t a8;
      a8[0] = f2bu(v0.x); a8[1] = f2bu(v0.y); a8[2] = f2bu(v0.z); a8[3] = f2bu(v0.w);
      a8[4] = f2bu(v1.x); a8[5] = f2bu(v1.y); a8[6] = f2bu(v1.z); a8[7] = f2bu(v1.w);
      *(u16x8_t*)((char*)sA + o) = a8;         // ds_write_b128
      int row = o >> 6, cb = o & 63;
      const u16* gB = Bw + (size_t)(tn * 128 + row) * 256 + kt * 32 + (cb >> 1);
      GLD16(gB, (char*)sB + o);
    }
    __syncthreads();
    bf16x8_t af[4], bfr[4];
#pragma unroll
    for (int i = 0; i < 4; ++i)
      af[i] = *(const bf16x8_t*)&sA[(wr * 64 + i * 16 + (lane & 15)) * 32 + (lane >> 4) * 8];
#pragma unroll
    for (int j = 0; j < 4; ++j)
      bfr[j] = *(const bf16x8_t*)&sB[(wc * 64 + j * 16 + (lane & 15)) * 32 + (lane >> 4) * 8];
#pragma unroll
    for (int i = 0; i < 4; ++i)
#pragma unroll
      for (int j = 0; j < 4; ++j)
        acc[i][j] = __builtin_amdgcn_mfma_f32_16x16x32_bf16(af[i], bfr[j], acc[i][j], 0, 0, 0);
  }
  const int r0 = tm * 128 + wr * 64, c0 = tn * 128 + wc * 64;
#pragma unroll
  for (int i = 0; i < 4; ++i)
#pragma unroll
    for (int j = 0; j < 4; ++j)
#pragma unroll
      for (int r = 0; r < 4; ++r) {
        int row = r0 + i * 16 + (lane >> 4) * 4 + r;
        int col = c0 + j * 16 + (lane & 15);
        int bwin = row / 294, n = row % 294;
        int sel = col >> 8, hh = (col >> 5) & 7, d = col & 31;
        C[((((size_t)bwin * 3 + sel) * 8 + hh) * 294 + n) * 32 + d] = f2bu(acc[i][j][r]);
      }
}

// ---------------- output-projection GEMM (A = aout bf16, scatter-f32 epilogue) --
__global__ __launch_bounds__(256, 2) void gemm_proj(const u16* __restrict__ A,
                                                    const u16* __restrict__ Bw,
                                                    float* __restrict__ Cf) {
  __shared__ u16 sA[128 * 32];
  __shared__ u16 sB[128 * 32];
  const int tid = threadIdx.x, lane = tid & 63, wave = tid >> 6;
  const int wr = wave >> 1, wc = wave & 1;
  const int tm = blockIdx.x, tn = blockIdx.y;
  fx4 acc[4][4] = {};
#pragma unroll 1
  for (int kt = 0; kt < 8; ++kt) {
    __syncthreads();
#pragma unroll
    for (int rnd = 0; rnd < 2; ++rnd) {
      int o = rnd * 4096 + tid * 16;
      int row = o >> 6, cb = o & 63;
      const u16* gA = A + (size_t)(tm * 128 + row) * 256 + kt * 32 + (cb >> 1);
      const u16* gB = Bw + (size_t)(tn * 128 + row) * 256 + kt * 32 + (cb >> 1);
      GLD16(gA, (char*)sA + o);
      GLD16(gB, (char*)sB + o);
    }
    __syncthreads();
    bf16x8_t af[4], bfr[4];
#pragma unroll
    for (int i = 0; i < 4; ++i)
      af[i] = *(const bf16x8_t*)&sA[(wr * 64 + i * 16 + (lane & 15)) * 32 + (lane >> 4) * 8];
#pragma unroll
    for (int j = 0; j < 4; ++j)
      bfr[j] = *(const bf16x8_t*)&sB[(wc * 64 + j * 16 + (lane & 15)) * 32 + (lane >> 4) * 8];
#pragma unroll
    for (int i = 0; i < 4; ++i)
#pragma unroll
      for (int j = 0; j < 4; ++j)
        acc[i][j] = __builtin_amdgcn_mfma_f32_16x16x32_bf16(af[i], bfr[j], acc[i][j], 0, 0, 0);
  }
  const int r0 = tm * 128 + wr * 64, c0 = tn * 128 + wc * 64;
#pragma unroll
  for (int i = 0; i < 4; ++i)
#pragma unroll
    for (int j = 0; j < 4; ++j)
#pragma unroll
      for (int r = 0; r < 4; ++r) {
        int row = r0 + i * 16 + (lane >> 4) * 4 + r;
        int col = c0 + j * 16 + (lane & 15);
        int b = row / 294, n = row % 294;
        int hx = b >> 4, wy = b & 15;
        int l = n / 49, rem = n % 49, w1 = rem / 7, w2 = rem % 7;
        size_t off = (((((size_t)l * 16 + hx) * 16 + wy) * 7 + w1) * 7 + w2) * 256 + col;
        Cf[off] = acc[i][j][r];
      }
}

// ---------------- fused attention: one block per (window, head) ----------------
// 320 threads = 5 waves x 2 strips (balanced). Head-major coalesced Q/K/V.
// Outer-t loop: K-tile loaded once, used by both strips. Streaming exp2 softmax.
__device__ __forceinline__ int vt_byte(int d, int tok) {
  return d * 656 + ((d >> 3) & 3) * 32 + tok * 2;
}

__global__ __launch_bounds__(320) void attn(const u16* __restrict__ qkv2,
                                            const float* __restrict__ bias_pre,
                                            u16* __restrict__ aout) {
  __shared__ __align__(16) u16 VT[10560];      // 21120 B
  const int blk = blockIdx.x;
  const int b = blk >> 3, h = blk & 7;
  const int tid = threadIdx.x, lane = tid & 63, wave = tid >> 6;  // wave 0..4
  const int l31 = lane & 31, g5 = lane >> 5;
  const u16* qb_ = qkv2 + ((size_t)(b * 3 + 0) * 8 + h) * 294 * 32;
  const u16* kb_ = qkv2 + ((size_t)(b * 3 + 1) * 8 + h) * 294 * 32;
  const u16* vb_ = qkv2 + ((size_t)(b * 3 + 2) * 8 + h) * 294 * 32;

  // stage swizzled V^T (coalesced reads; zero-fill padded tokens 294..319)
  for (int i = tid; i < 1280; i += 320) {
    int tok = i >> 2, c8 = (i & 3) * 8;
    u16x8_t v;
    if (tok < 294) {
      v = *(const u16x8_t*)(vb_ + tok * 32 + c8);
    } else {
#pragma unroll
      for (int j = 0; j < 8; ++j) v[j] = 0;
    }
#pragma unroll
    for (int j = 0; j < 8; ++j)
      *(u16*)((char*)VT + vt_byte(c8 + j, tok)) = v[j];
  }
  __syncthreads();

  const int s0 = wave, s1 = wave + 5;
  int qr0 = s0 * 32 + l31; if (qr0 > 293) qr0 = 293;
  int qr1 = s1 * 32 + l31; if (qr1 > 293) qr1 = 293;
  const u16* q0p = qb_ + qr0 * 32;
  const u16* q1p = qb_ + qr1 * 32;
  bf16x8_t qa0 = *(const bf16x8_t*)(q0p + g5 * 8);
  bf16x8_t qa1 = *(const bf16x8_t*)(q0p + 16 + g5 * 8);
  bf16x8_t qb0 = *(const bf16x8_t*)(q1p + g5 * 8);
  bf16x8_t qb1 = *(const bf16x8_t*)(q1p + 16 + g5 * 8);

  fx16 O0, O1;
#pragma unroll
  for (int r = 0; r < 16; ++r) { O0[r] = 0.f; O1[r] = 0.f; }
  float sva0 = 0.f, svb0 = 0.f, sva1 = 0.f, svb1 = 0.f;
  const float* bp0 = bias_pre + ((size_t)(h * 10 + s0) * 10) * 1024 + lane * 16;
  const float* bp1 = bias_pre + ((size_t)(h * 10 + s1) * 10) * 1024 + lane * 16;

#pragma unroll 1
  for (int t = 0; t < 10; ++t) {
    int krc = t * 32 + l31; if (krc > 293) krc = 293;
    const u16* kp = kb_ + krc * 32;
    bf16x8_t kf0 = *(const bf16x8_t*)(kp + g5 * 8);
    bf16x8_t kf1 = *(const bf16x8_t*)(kp + 16 + g5 * 8);
    bf16x8_t vf0 = *(const bf16x8_t*)((char*)VT + vt_byte(l31, t * 32 + g5 * 8));
    bf16x8_t vf1 = *(const bf16x8_t*)((char*)VT + vt_byte(l31, t * 32 + 16 + g5 * 8));

    // ---- strip 0 ----
    {
      const float* bp = bp0 + t * 1024;
      fx16 a;
#pragma unroll
      for (int q4 = 0; q4 < 4; ++q4) {
        fx4 bv = *(const fx4*)(bp + q4 * 4);
        a[q4 * 4 + 0] = bv[0]; a[q4 * 4 + 1] = bv[1];
        a[q4 * 4 + 2] = bv[2]; a[q4 * 4 + 3] = bv[3];
      }
      a = __builtin_amdgcn_mfma_f32_32x32x16_bf16(kf0, qa0, a, 0, 0, 0);
      a = __builtin_amdgcn_mfma_f32_32x32x16_bf16(kf1, qa1, a, 0, 0, 0);
      u32 pk[8];
#pragma unroll
      for (int j = 0; j < 8; ++j) {
        float e0 = __builtin_exp2f(a[2 * j]);
        float e1 = __builtin_exp2f(a[2 * j + 1]);
        sva0 += e0; svb0 += e1;
        pk[j] = (u32)f2bu(e0) | ((u32)f2bu(e1) << 16);
      }
      u32 w0 = pk[0], w1 = pk[1], w2 = pk[2], w3 = pk[3];
      plswap(w0, w2); plswap(w1, w3);
      u32x4_t wv; wv[0] = w0; wv[1] = w1; wv[2] = w2; wv[3] = w3;
      O0 = __builtin_amdgcn_mfma_f32_32x32x16_bf16(__builtin_bit_cast(bf16x8_t, wv), vf0, O0, 0, 0, 0);
      u32 y0 = pk[4], y1 = pk[5], y2 = pk[6], y3 = pk[7];
      plswap(y0, y2); plswap(y1, y3);
      u32x4_t yv; yv[0] = y0; yv[1] = y1; yv[2] = y2; yv[3] = y3;
      O0 = __builtin_amdgcn_mfma_f32_32x32x16_bf16(__builtin_bit_cast(bf16x8_t, yv), vf1, O0, 0, 0, 0);
    }
    // ---- strip 1 ----
    {
      const float* bp = bp1 + t * 1024;
      fx16 a;
#pragma unroll
      for (int q4 = 0; q4 < 4; ++q4) {
        fx4 bv = *(const fx4*)(bp + q4 * 4);
        a[q4 * 4 + 0] = bv[0]; a[q4 * 4 + 1] = bv[1];
        a[q4 * 4 + 2] = bv[2]; a[q4 * 4 + 3] = bv[3];
      }
      a = __builtin_amdgcn_mfma_f32_32x32x16_bf16(kf0, qb0, a, 0, 0, 0);
      a = __builtin_amdgcn_mfma_f32_32x32x16_bf16(kf1, qb1, a, 0, 0, 0);
      u32 pk[8];
#pragma unroll
      for (int j = 0; j < 8; ++j) {
        float e0 = __builtin_exp2f(a[2 * j]);
        float e1 = __builtin_exp2f(a[2 * j + 1]);
        sva1 += e0; svb1 += e1;
        pk[j] = (u32)f2bu(e0) | ((u32)f2bu(e1) << 16);
      }
      u32 w0 = pk[0], w1 = pk[1], w2 = pk[2], w3 = pk[3];
      plswap(w0, w2); plswap(w1, w3);
      u32x4_t wv; wv[0] = w0; wv[1] = w1; wv[2] = w2; wv[3] = w3;
      O1 = __builtin_amdgcn_mfma_f32_32x32x16_bf16(__builtin_bit_cast(bf16x8_t, wv), vf0, O1, 0, 0, 0);
      u32 y0 = pk[4], y1 = pk[5], y2 = pk[6], y3 = pk[7];
      plswap(y0, y2); plswap(y1, y3);
      u32x4_t yv; yv[0] = y0; yv[1] = y1; yv[2] = y2; yv[3] = y3;
      O1 = __builtin_amdgcn_mfma_f32_32x32x16_bf16(__builtin_bit_cast(bf16x8_t, yv), vf1, O1, 0, 0, 0);
    }
  }

  float sv0 = sva0 + svb0; sv0 += __shfl_xor(sv0, 32);
  float sv1 = sva1 + svb1; sv1 += __shfl_xor(sv1, 32);
  float inv0 = 1.0f / sv0, inv1 = 1.0f / sv1;

  // store: C-layout row=(r&3)+8*(r>>2)+4*g5 = query, col=l31 = dim
#pragma unroll
  for (int r = 0; r < 16; ++r) {
    int qrow = (r & 3) + 8 * (r >> 2) + 4 * g5;
    int qo0 = s0 * 32 + qrow;
    float iv0 = __shfl(inv0, qrow);
    if (qo0 < 294)
      aout[((size_t)b * 294 + qo0) * 256 + h * 32 + l31] = f2bu(O0[r] * iv0);
    int qo1 = s1 * 32 + qrow;
    float iv1 = __shfl(inv1, qrow);
    if (qo1 < 294)
      aout[((size_t)b * 294 + qo1) * 256 + h * 32 + l31] = f2bu(O1[r] * iv1);
  }
}

extern "C" void kernel_launch(void* const* d_in, const int* in_sizes, int n_in,
                              void* d_out, int out_size, void* d_ws, size_t ws_size,
                              hipStream_t stream) {
  (void)in_sizes; (void)n_in; (void)out_size; (void)ws_size;
  const float* x    = (const float*)d_in[0];
  const float* wqkv = (const float*)d_in[1];
  const float* wout = (const float*)d_in[2];
  const float* btab = (const float*)d_in[3];
  float* out = (float*)d_out;
  char* ws = (char*)d_ws;
  u16* aout   = (u16*)(ws);                    // 75264*256*2   = 38,535,168
  u16* bqkv   = (u16*)(ws + 38535168);         // 768*256*2     =    393,216
  u16* bwout  = (u16*)(ws + 38928384);         // 256*256*2     =    131,072
  float* biasp = (float*)(ws + 39059456);      // 51200*16*4    =  3,276,800
  u16* qkv2   = (u16*)(ws + 42336256);         // 75264*768*2   = 115,605,504 (tot ~158MB)

  prep_w<<<1024, 256, 0, stream>>>(wqkv, wout, bqkv, bwout);
  prep_bias<<<200, 256, 0, stream>>>(btab, biasp);
  gemm_qkv<<<dim3(588, 6), 256, 0, stream>>>(x, bqkv, qkv2);
  attn<<<2048, 320, 0, stream>>>(qkv2, biasp, aout);
  gemm_proj<<<dim3(588, 2), 256, 0, stream>>>(aout, bwout, out);
}